// Round 4
// baseline (1049.696 us; speedup 1.0000x reference)
//
#include <hip/hip_runtime.h>
#include <hip/hip_bf16.h>

typedef __bf16 bf16x8 __attribute__((ext_vector_type(8)));
typedef __bf16 bf16x4 __attribute__((ext_vector_type(4)));
typedef __bf16 bf16x2 __attribute__((ext_vector_type(2)));
typedef float f32x4 __attribute__((ext_vector_type(4)));

#define BM 128
#define BN 128
#define BK 32

__device__ __forceinline__ void gload16(const __bf16* g, __bf16* l) {
    __builtin_amdgcn_global_load_lds((const __attribute__((address_space(1))) void*)g,
                                     (__attribute__((address_space(3))) void*)l, 16, 0, 0);
}

__device__ __forceinline__ float gelu_f(float v) {
    float z = 0.7978845608028654f * (v + 0.044715f * v * v * v);
    float e = __expf(2.f * z);
    return 0.5f * v * (2.f - 2.f / (e + 1.f));  // 0.5*v*(1+tanh(z)), overflow-safe
}

// ---------------- diagnostic fill (fp32 out) ----------------
__global__ __launch_bounds__(256) void diag_kernel(float* out, int n, float v) {
    int i = blockIdx.x * 256 + threadIdx.x;
    if (i < n) out[i] = v;
}

// ---------------- fp32 -> bf16 conversion ----------------
__global__ __launch_bounds__(256) void cvt_kernel(
    const float* __restrict__ src, __bf16* __restrict__ dst, int n4)
{
    int i = blockIdx.x * 256 + threadIdx.x;
    if (i < n4) {
        float4 v = ((const float4*)src)[i];
        bf16x4 o;
        o[0] = (__bf16)v.x; o[1] = (__bf16)v.y; o[2] = (__bf16)v.z; o[3] = (__bf16)v.w;
        ((bf16x4*)dst)[i] = o;
    }
}

// ---------------- LayerNorm: fp32 in, bf16 out; one block per row of 1024 ----------------
__global__ __launch_bounds__(256) void ln_kernel(
    const float* __restrict__ x, const float* __restrict__ g,
    const float* __restrict__ bta, __bf16* __restrict__ out)
{
    const int row = blockIdx.x, t = threadIdx.x;
    const float* xr = x + (size_t)row * 1024;
    float4 xv = ((const float4*)xr)[t];
    float f[4] = {xv.x, xv.y, xv.z, xv.w};
    float s = f[0] + f[1] + f[2] + f[3];
    float ss = f[0]*f[0] + f[1]*f[1] + f[2]*f[2] + f[3]*f[3];
#pragma unroll
    for (int off = 32; off; off >>= 1) {
        s  += __shfl_xor(s, off, 64);
        ss += __shfl_xor(ss, off, 64);
    }
    __shared__ float red[8];
    int lane = t & 63, w = t >> 6;
    if (lane == 0) { red[w] = s; red[4 + w] = ss; }
    __syncthreads();
    s  = red[0] + red[1] + red[2] + red[3];
    ss = red[4] + red[5] + red[6] + red[7];
    float mu = s * (1.f / 1024.f);
    float var = ss * (1.f / 1024.f) - mu * mu;
    float rstd = rsqrtf(fmaxf(var, 0.f) + 1e-5f);
    float4 gv = ((const float4*)g)[t];
    float4 bv = ((const float4*)bta)[t];
    bf16x4 ov;
    ov[0] = (__bf16)((f[0] - mu) * rstd * gv.x + bv.x);
    ov[1] = (__bf16)((f[1] - mu) * rstd * gv.y + bv.y);
    ov[2] = (__bf16)((f[2] - mu) * rstd * gv.z + bv.z);
    ov[3] = (__bf16)((f[3] - mu) * rstd * gv.w + bv.w);
    ((bf16x4*)(out + (size_t)row * 1024))[t] = ov;
}

// ---------------- GEMM: C[M,N] = A[M,K](bf16) @ B[K,N](bf16) + bias(f32) ----------------
// EPI: 0 = bias, 1 = bias + fp32 residual, 2 = bias + gelu
// OUT32: true -> fp32 C, false -> bf16 C
template <int EPI, bool OUT32>
__global__ __launch_bounds__(256, 2) void gemm_kn_kernel(
    const __bf16* __restrict__ A, const __bf16* __restrict__ B,
    const float* __restrict__ bias, const float* __restrict__ res,
    void* __restrict__ Cp, int M, int N, int K)
{
    __shared__ __align__(16) __bf16 lA[BM * BK];  // phys = kc*1024 + row*8 + j
    __shared__ __align__(16) __bf16 lB[BN * BK];  // phys = n*32 + k
    const int t = threadIdx.x;
    const int lane = t & 63;
    const int wave = t >> 6;
    const int wm = wave >> 1, wn = wave & 1;
    const int q4 = lane >> 4, r16 = lane & 15;
    const int bm = blockIdx.y * BM, bn = blockIdx.x * BN;

    // A staging (global_load_lds, k-contiguous)
    const int srow = t & 127;
    const int skc = t >> 7;  // 0..1; second call adds 2
    const __bf16* ga0 = A + (size_t)(bm + srow) * K + skc * 8;
    const __bf16* ga1 = A + (size_t)(bm + srow) * K + (skc + 2) * 8;

    // B staging (register pair-transpose): thread owns k-pair kp2, n-group ng
    const int kp2 = (t >> 4) * 2;   // 0,2,..,30
    const int ng  = t & 15;         // n0 = ng*8
    const __bf16* gb = B + (size_t)kp2 * N + bn + ng * 8;

    f32x4 acc[4][4];
    f32x4 zero4 = {0.f, 0.f, 0.f, 0.f};
#pragma unroll
    for (int mi = 0; mi < 4; ++mi)
#pragma unroll
        for (int ni = 0; ni < 4; ++ni) acc[mi][ni] = zero4;

    for (int k0 = 0; k0 < K; k0 += BK) {
        __syncthreads();
        gload16(ga0, &lA[t * 8]);
        gload16(ga1, &lA[t * 8 + 2048]);
        ga0 += BK; ga1 += BK;
        bf16x8 r0 = *(const bf16x8*)gb;
        bf16x8 r1 = *(const bf16x8*)(gb + N);
        gb += (size_t)BK * N;
#pragma unroll
        for (int j = 0; j < 8; ++j) {
            bf16x2 pr; pr[0] = r0[j]; pr[1] = r1[j];
            *(bf16x2*)&lB[(ng * 8 + j) * 32 + kp2] = pr;
        }
        __syncthreads();
        bf16x8 af[4], bfr[4];
#pragma unroll
        for (int i = 0; i < 4; ++i)
            af[i] = *(const bf16x8*)&lA[q4 * 1024 + (wm * 64 + i * 16 + r16) * 8];
#pragma unroll
        for (int i = 0; i < 4; ++i)
            bfr[i] = *(const bf16x8*)&lB[(wn * 64 + i * 16 + r16) * 32 + q4 * 8];
#pragma unroll
        for (int mi = 0; mi < 4; ++mi)
#pragma unroll
            for (int ni = 0; ni < 4; ++ni)
                acc[mi][ni] = __builtin_amdgcn_mfma_f32_16x16x32_bf16(
                    af[mi], bfr[ni], acc[mi][ni], 0, 0, 0);
    }

#pragma unroll
    for (int mi = 0; mi < 4; ++mi) {
#pragma unroll
        for (int ni = 0; ni < 4; ++ni) {
#pragma unroll
            for (int i = 0; i < 4; ++i) {
                int r = bm + wm * 64 + mi * 16 + q4 * 4 + i;
                int c = bn + wn * 64 + ni * 16 + r16;
                float v = acc[mi][ni][i] + bias[c];
                if (EPI == 1) v += res[(size_t)r * N + c];
                if (EPI == 2) v = gelu_f(v);
                if (OUT32) ((float*)Cp)[(size_t)r * N + c] = v;
                else       ((__bf16*)Cp)[(size_t)r * N + c] = (__bf16)v;
            }
        }
    }
}

// ---------------- Flash attention (causal), HD=64, T=2048, NH=16; bf16 in/out ----------------
__global__ __launch_bounds__(256) void attn_kernel(
    const __bf16* __restrict__ qkv, __bf16* __restrict__ attnb)
{
    __shared__ __align__(16) __bf16 lK[2048];    // phys = dc*256 + key*8 + j
    __shared__ __align__(16) __bf16 lV[2048];    // phys = kc*512 + d*8 + j
    __shared__ __align__(16) __bf16 lP[4][512];  // per-wave: phys = kc*128 + row*8 + j

    const int t = threadIdx.x, lane = t & 63, w = t >> 6;
    const int q4 = lane >> 4, r16 = lane & 15;
    const int b = blockIdx.y >> 4, h = blockIdx.y & 15;
    const int qb = blockIdx.x * 64;
    const __bf16* Qb = qkv + (size_t)b * 2048 * 3072 + h * 64;
    const __bf16* Kb = Qb + 1024;
    const __bf16* Vb = Qb + 2048;

    const int qrow = qb + w * 16 + r16;
    bf16x8 qf0 = *(const bf16x8*)(Qb + (size_t)qrow * 3072 + q4 * 8);
    bf16x8 qf1 = *(const bf16x8*)(Qb + (size_t)qrow * 3072 + 32 + q4 * 8);

    f32x4 zero4 = {0.f, 0.f, 0.f, 0.f};
    f32x4 o[4] = {zero4, zero4, zero4, zero4};
    float m_i[4], l_i[4];
#pragma unroll
    for (int i = 0; i < 4; ++i) { m_i[i] = -3e4f; l_i[i] = 0.f; }

    const int sdc = t >> 5, skey = t & 31;
    const int vkc = t >> 6, vd = t & 63;

    for (int kb = 0; kb < qb + 64; kb += 32) {
        __syncthreads();
        bf16x8 kt = *(const bf16x8*)(Kb + (size_t)(kb + skey) * 3072 + sdc * 8);
        *(bf16x8*)&lK[t * 8] = kt;
        bf16x8 vt;
#pragma unroll
        for (int j = 0; j < 8; ++j)
            vt[j] = Vb[(size_t)(kb + vkc * 8 + j) * 3072 + vd];
        *(bf16x8*)&lV[vkc * 512 + vd * 8] = vt;
        __syncthreads();

        f32x4 s0 = zero4, s1 = zero4;
        bf16x8 kf00 = *(const bf16x8*)&lK[q4 * 256 + r16 * 8];
        bf16x8 kf01 = *(const bf16x8*)&lK[q4 * 256 + (16 + r16) * 8];
        bf16x8 kf10 = *(const bf16x8*)&lK[(4 + q4) * 256 + r16 * 8];
        bf16x8 kf11 = *(const bf16x8*)&lK[(4 + q4) * 256 + (16 + r16) * 8];
        s0 = __builtin_amdgcn_mfma_f32_16x16x32_bf16(qf0, kf00, s0, 0, 0, 0);
        s0 = __builtin_amdgcn_mfma_f32_16x16x32_bf16(qf1, kf10, s0, 0, 0, 0);
        s1 = __builtin_amdgcn_mfma_f32_16x16x32_bf16(qf0, kf01, s1, 0, 0, 0);
        s1 = __builtin_amdgcn_mfma_f32_16x16x32_bf16(qf1, kf11, s1, 0, 0, 0);

        const int row0 = qb + w * 16 + q4 * 4;
        bool um0[4], um1[4];
        float a0[4], a1[4], mt[4];
#pragma unroll
        for (int i = 0; i < 4; ++i) {
            um0[i] = (kb + r16) <= (row0 + i);
            um1[i] = (kb + 16 + r16) <= (row0 + i);
            a0[i] = um0[i] ? s0[i] * 0.125f : -3e4f;
            a1[i] = um1[i] ? s1[i] * 0.125f : -3e4f;
            mt[i] = fmaxf(a0[i], a1[i]);
        }
#pragma unroll
        for (int off = 8; off; off >>= 1)
#pragma unroll
            for (int i = 0; i < 4; ++i)
                mt[i] = fmaxf(mt[i], __shfl_xor(mt[i], off, 64));
        float alpha[4];
#pragma unroll
        for (int i = 0; i < 4; ++i) {
            float mn = fmaxf(m_i[i], mt[i]);
            alpha[i] = __expf(m_i[i] - mn);
            m_i[i] = mn;
        }
        float p0[4], p1[4], rs[4];
#pragma unroll
        for (int i = 0; i < 4; ++i) {
            p0[i] = um0[i] ? __expf(a0[i] - m_i[i]) : 0.f;
            p1[i] = um1[i] ? __expf(a1[i] - m_i[i]) : 0.f;
            rs[i] = p0[i] + p1[i];
        }
#pragma unroll
        for (int off = 8; off; off >>= 1)
#pragma unroll
            for (int i = 0; i < 4; ++i) rs[i] += __shfl_xor(rs[i], off, 64);
#pragma unroll
        for (int i = 0; i < 4; ++i) l_i[i] = l_i[i] * alpha[i] + rs[i];
#pragma unroll
        for (int ci = 0; ci < 4; ++ci)
#pragma unroll
            for (int i = 0; i < 4; ++i) o[ci][i] *= alpha[i];

        // P: C-layout (row=q4*4+i, col=ki*16+r16) -> A-layout via LDS
#pragma unroll
        for (int i = 0; i < 4; ++i) {
            lP[w][(0 * 2 + (r16 >> 3)) * 128 + (q4 * 4 + i) * 8 + (r16 & 7)] = (__bf16)p0[i];
            lP[w][(1 * 2 + (r16 >> 3)) * 128 + (q4 * 4 + i) * 8 + (r16 & 7)] = (__bf16)p1[i];
        }
        __syncthreads();
        bf16x8 pf = *(const bf16x8*)&lP[w][q4 * 128 + r16 * 8];
#pragma unroll
        for (int ci = 0; ci < 4; ++ci) {
            bf16x8 vf = *(const bf16x8*)&lV[q4 * 512 + (ci * 16 + r16) * 8];
            o[ci] = __builtin_amdgcn_mfma_f32_16x16x32_bf16(pf, vf, o[ci], 0, 0, 0);
        }
    }

#pragma unroll
    for (int ci = 0; ci < 4; ++ci)
#pragma unroll
        for (int i = 0; i < 4; ++i) {
            int trow = qb + w * 16 + q4 * 4 + i;
            float inv_l = (l_i[i] > 0.f) ? (1.f / l_i[i]) : 0.f;
            attnb[(size_t)(b * 2048 + trow) * 1024 + h * 64 + ci * 16 + r16] =
                (__bf16)(o[ci][i] * inv_l);
        }
}

// ---------------- launcher ----------------
extern "C" void kernel_launch(void* const* d_in, const int* in_sizes, int n_in,
                              void* d_out, int out_size, void* d_ws, size_t ws_size,
                              hipStream_t stream)
{
    const float* x      = (const float*)d_in[0];
    const float* ln1_g  = (const float*)d_in[1];
    const float* ln1_b  = (const float*)d_in[2];
    const float* w_qkv  = (const float*)d_in[3];
    const float* b_qkv  = (const float*)d_in[4];
    const float* w_proj = (const float*)d_in[5];
    const float* b_proj = (const float*)d_in[6];
    const float* ln2_g  = (const float*)d_in[7];
    const float* ln2_b  = (const float*)d_in[8];
    const float* w_fc   = (const float*)d_in[9];
    const float* b_fc   = (const float*)d_in[10];
    const float* w_mlp  = (const float*)d_in[11];
    const float* b_mlp  = (const float*)d_in[12];
    float* out = (float*)d_out;

    const size_t MiB = (size_t)1 << 20;
    const size_t need = 136 * MiB;
    if (ws_size < need) {
        float v = 1000.f + (float)(ws_size >> 20);  // report ws_size via absmax
        diag_kernel<<<(out_size + 255) / 256, 256, 0, stream>>>(out, out_size, v);
        return;
    }

    char* ws = (char*)d_ws;
    __bf16* bufA  = (__bf16*)(ws);              // 16 MiB: h -> attnb -> h2
    __bf16* bufB  = (__bf16*)(ws + 16 * MiB);   // 64 MiB: qkvb(48) -> ffb(64)
    float*  x1    = (float*) (ws + 80 * MiB);   // 32 MiB fp32 residual stream
    __bf16* cwqkv = (__bf16*)(ws + 112 * MiB);  // 6 MiB
    __bf16* cwproj= (__bf16*)(ws + 118 * MiB);  // 2 MiB
    __bf16* cwfc  = (__bf16*)(ws + 120 * MiB);  // 8 MiB
    __bf16* cwmlp = (__bf16*)(ws + 128 * MiB);  // 8 MiB

    cvt_kernel<<<3072, 256, 0, stream>>>(w_qkv,  cwqkv,  1024 * 3072 / 4);
    cvt_kernel<<<1024, 256, 0, stream>>>(w_proj, cwproj, 1024 * 1024 / 4);
    cvt_kernel<<<4096, 256, 0, stream>>>(w_fc,   cwfc,   1024 * 4096 / 4);
    cvt_kernel<<<4096, 256, 0, stream>>>(w_mlp,  cwmlp,  4096 * 1024 / 4);

    ln_kernel<<<8192, 256, 0, stream>>>(x, ln1_g, ln1_b, bufA);
    gemm_kn_kernel<0, false><<<dim3(24, 64), 256, 0, stream>>>(
        bufA, cwqkv, b_qkv, nullptr, bufB, 8192, 3072, 1024);
    attn_kernel<<<dim3(32, 64), 256, 0, stream>>>(bufB, bufA);
    gemm_kn_kernel<1, true><<<dim3(8, 64), 256, 0, stream>>>(
        bufA, cwproj, b_proj, x, x1, 8192, 1024, 1024);
    ln_kernel<<<8192, 256, 0, stream>>>(x1, ln2_g, ln2_b, bufA);
    gemm_kn_kernel<2, false><<<dim3(32, 64), 256, 0, stream>>>(
        bufA, cwfc, b_fc, nullptr, bufB, 8192, 4096, 1024);
    gemm_kn_kernel<1, true><<<dim3(8, 64), 256, 0, stream>>>(
        bufB, cwmlp, b_mlp, x1, out, 8192, 1024, 4096);
}

// Round 5
// 806.721 us; speedup vs baseline: 1.3012x; 1.3012x over previous
//
#include <hip/hip_runtime.h>
#include <hip/hip_bf16.h>

typedef __bf16 bf16x8 __attribute__((ext_vector_type(8)));
typedef __bf16 bf16x4 __attribute__((ext_vector_type(4)));
typedef float f32x4 __attribute__((ext_vector_type(4)));

#define BM 128
#define BN 128
#define BK 32

__device__ __forceinline__ void gload16(const __bf16* g, __bf16* l) {
    __builtin_amdgcn_global_load_lds((const __attribute__((address_space(1))) void*)g,
                                     (__attribute__((address_space(3))) void*)l, 16, 0, 0);
}

__device__ __forceinline__ float gelu_f(float v) {
    float z = 0.7978845608028654f * (v + 0.044715f * v * v * v);
    float e = __expf(2.f * z);
    return 0.5f * v * (2.f - 2.f / (e + 1.f));  // 0.5*v*(1+tanh(z)), overflow-safe
}

// ---------------- diagnostic fill (fp32 out) ----------------
__global__ __launch_bounds__(256) void diag_kernel(float* out, int n, float v) {
    int i = blockIdx.x * 256 + threadIdx.x;
    if (i < n) out[i] = v;
}

// ---------------- fused fp32->bf16 convert + transpose: in[K,N] -> out[N,K] ----------------
__global__ __launch_bounds__(256) void cvtT_kernel(
    const float* __restrict__ in, __bf16* __restrict__ out, int K, int N)
{
    __shared__ __bf16 tile[32][33];
    int bx = blockIdx.x * 32, by = blockIdx.y * 32;  // bx: n, by: k
    int tx = threadIdx.x & 31, ty = threadIdx.x >> 5;  // 32 x 8
#pragma unroll
    for (int i = 0; i < 32; i += 8)
        tile[ty + i][tx] = (__bf16)in[(size_t)(by + ty + i) * N + bx + tx];
    __syncthreads();
#pragma unroll
    for (int i = 0; i < 32; i += 8)
        out[(size_t)(bx + ty + i) * K + by + tx] = tile[tx][ty + i];
}

// ---------------- LayerNorm: fp32 in, bf16 out; one block per row of 1024 ----------------
__global__ __launch_bounds__(256) void ln_kernel(
    const float* __restrict__ x, const float* __restrict__ g,
    const float* __restrict__ bta, __bf16* __restrict__ out)
{
    const int row = blockIdx.x, t = threadIdx.x;
    const float* xr = x + (size_t)row * 1024;
    float4 xv = ((const float4*)xr)[t];
    float f[4] = {xv.x, xv.y, xv.z, xv.w};
    float s = f[0] + f[1] + f[2] + f[3];
    float ss = f[0]*f[0] + f[1]*f[1] + f[2]*f[2] + f[3]*f[3];
#pragma unroll
    for (int off = 32; off; off >>= 1) {
        s  += __shfl_xor(s, off, 64);
        ss += __shfl_xor(ss, off, 64);
    }
    __shared__ float red[8];
    int lane = t & 63, w = t >> 6;
    if (lane == 0) { red[w] = s; red[4 + w] = ss; }
    __syncthreads();
    s  = red[0] + red[1] + red[2] + red[3];
    ss = red[4] + red[5] + red[6] + red[7];
    float mu = s * (1.f / 1024.f);
    float var = ss * (1.f / 1024.f) - mu * mu;
    float rstd = rsqrtf(fmaxf(var, 0.f) + 1e-5f);
    float4 gv = ((const float4*)g)[t];
    float4 bv = ((const float4*)bta)[t];
    bf16x4 ov;
    ov[0] = (__bf16)((f[0] - mu) * rstd * gv.x + bv.x);
    ov[1] = (__bf16)((f[1] - mu) * rstd * gv.y + bv.y);
    ov[2] = (__bf16)((f[2] - mu) * rstd * gv.z + bv.z);
    ov[3] = (__bf16)((f[3] - mu) * rstd * gv.w + bv.w);
    ((bf16x4*)(out + (size_t)row * 1024))[t] = ov;
}

// ---------------- GEMM (m97): C[M,N] = A[M,K](bf16) @ BT[N,K]^T(bf16) + bias(f32) ----------------
// EPI: 0 = bias, 1 = bias + fp32 residual, 2 = bias + gelu ; OUT32: fp32 vs bf16 C
template <int EPI, bool OUT32>
__global__ __launch_bounds__(256, 2) void gemm_bt_kernel(
    const __bf16* __restrict__ A, const __bf16* __restrict__ BT,
    const float* __restrict__ bias, const float* __restrict__ res,
    void* __restrict__ Cp, int M, int N, int K)
{
    __shared__ __align__(16) __bf16 lA[BM * BK];  // phys = kc*1024 + row*8 + j
    __shared__ __align__(16) __bf16 lB[BN * BK];  // same layout (rows = n)
    const int t = threadIdx.x;
    const int lane = t & 63;
    const int wave = t >> 6;
    const int wm = wave >> 1, wn = wave & 1;
    const int q4 = lane >> 4, r16 = lane & 15;
    const int bm = blockIdx.y * BM, bn = blockIdx.x * BN;

    const int srow = t & 127;
    const int skc = t >> 7;  // 0..1; second call adds 2
    const __bf16* ga0 = A + (size_t)(bm + srow) * K + skc * 8;
    const __bf16* ga1 = A + (size_t)(bm + srow) * K + (skc + 2) * 8;
    const __bf16* gb0 = BT + (size_t)(bn + srow) * K + skc * 8;
    const __bf16* gb1 = BT + (size_t)(bn + srow) * K + (skc + 2) * 8;

    f32x4 acc[4][4];
    f32x4 zero4 = {0.f, 0.f, 0.f, 0.f};
#pragma unroll
    for (int mi = 0; mi < 4; ++mi)
#pragma unroll
        for (int ni = 0; ni < 4; ++ni) acc[mi][ni] = zero4;

    for (int k0 = 0; k0 < K; k0 += BK) {
        __syncthreads();
        gload16(ga0, &lA[t * 8]);
        gload16(ga1, &lA[t * 8 + 2048]);
        gload16(gb0, &lB[t * 8]);
        gload16(gb1, &lB[t * 8 + 2048]);
        ga0 += BK; ga1 += BK; gb0 += BK; gb1 += BK;
        __syncthreads();
        bf16x8 af[4], bfr[4];
#pragma unroll
        for (int i = 0; i < 4; ++i)
            af[i] = *(const bf16x8*)&lA[q4 * 1024 + (wm * 64 + i * 16 + r16) * 8];
#pragma unroll
        for (int i = 0; i < 4; ++i)
            bfr[i] = *(const bf16x8*)&lB[q4 * 1024 + (wn * 64 + i * 16 + r16) * 8];
#pragma unroll
        for (int mi = 0; mi < 4; ++mi)
#pragma unroll
            for (int ni = 0; ni < 4; ++ni)
                acc[mi][ni] = __builtin_amdgcn_mfma_f32_16x16x32_bf16(
                    af[mi], bfr[ni], acc[mi][ni], 0, 0, 0);
    }

#pragma unroll
    for (int mi = 0; mi < 4; ++mi) {
#pragma unroll
        for (int ni = 0; ni < 4; ++ni) {
#pragma unroll
            for (int i = 0; i < 4; ++i) {
                int r = bm + wm * 64 + mi * 16 + q4 * 4 + i;
                int c = bn + wn * 64 + ni * 16 + r16;
                float v = acc[mi][ni][i] + bias[c];
                if (EPI == 1) v += res[(size_t)r * N + c];
                if (EPI == 2) v = gelu_f(v);
                if (OUT32) ((float*)Cp)[(size_t)r * N + c] = v;
                else       ((__bf16*)Cp)[(size_t)r * N + c] = (__bf16)v;
            }
        }
    }
}

// ---------------- Flash attention (causal), HD=64, T=2048, NH=16; KT=128 ----------------
// grid: (32, B*NH), longest-first qtile order; block 256 (4 waves x 16 q rows)
__global__ __launch_bounds__(256) void attn_kernel(
    const __bf16* __restrict__ qkv, __bf16* __restrict__ attnb)
{
    __shared__ __align__(16) __bf16 lK[8192];     // (key,d): phys = (d>>3)*1024 + key*8 + (d&7)
    __shared__ __align__(16) __bf16 lV[8192];     // (key,d): phys = (key>>3)*512 + d*8 + (key&7)
    __shared__ __align__(16) __bf16 lP[4][2048];  // per-wave (row,key): (key>>3)*128 + row*8 + (key&7)

    const int t = threadIdx.x, lane = t & 63, w = t >> 6;
    const int q4 = lane >> 4, r16 = lane & 15;
    const int b = blockIdx.y >> 4, h = blockIdx.y & 15;
    const int qt = 31 - blockIdx.x;       // longest-running blocks dispatch first
    const int qb = qt * 64;
    const __bf16* Qb = qkv + (size_t)b * 2048 * 3072 + h * 64;
    const __bf16* Kb = Qb + 1024;
    const __bf16* Vb = Qb + 2048;

    const int qrow = qb + w * 16 + r16;
    bf16x8 qf0 = *(const bf16x8*)(Qb + (size_t)qrow * 3072 + q4 * 8);
    bf16x8 qf1 = *(const bf16x8*)(Qb + (size_t)qrow * 3072 + 32 + q4 * 8);

    f32x4 zero4 = {0.f, 0.f, 0.f, 0.f};
    f32x4 o[4] = {zero4, zero4, zero4, zero4};
    float m_i[4], l_i[4];
#pragma unroll
    for (int i = 0; i < 4; ++i) { m_i[i] = -1e30f; l_i[i] = 0.f; }

    const int skey = t & 127;      // K staging
    const int svd  = t & 63;       // V staging

    for (int kb = 0; kb < qb + 64; kb += 128) {
        __syncthreads();
#pragma unroll
        for (int c = 0; c < 4; ++c)
            gload16(Kb + (size_t)(kb + skey) * 3072 + (c * 2 + (t >> 7)) * 8,
                    &lK[c * 2048 + t * 8]);
#pragma unroll
        for (int c = 0; c < 4; ++c) {
            int kc = c * 4 + (t >> 6);
            bf16x8 vt;
#pragma unroll
            for (int j = 0; j < 8; ++j)
                vt[j] = Vb[(size_t)(kb + kc * 8 + j) * 3072 + svd];
            *(bf16x8*)&lV[kc * 512 + svd * 8] = vt;
        }
        __syncthreads();

        // QK^T: S[16 q x 128 key] per wave
        f32x4 s[8];
#pragma unroll
        for (int kg = 0; kg < 8; ++kg) {
            bf16x8 kfA = *(const bf16x8*)&lK[q4 * 1024 + (kg * 16 + r16) * 8];
            bf16x8 kfB = *(const bf16x8*)&lK[(4 + q4) * 1024 + (kg * 16 + r16) * 8];
            s[kg] = __builtin_amdgcn_mfma_f32_16x16x32_bf16(qf0, kfA, zero4, 0, 0, 0);
            s[kg] = __builtin_amdgcn_mfma_f32_16x16x32_bf16(qf1, kfB, s[kg], 0, 0, 0);
        }

        const int row0 = qb + w * 16 + q4 * 4;
        const bool interior = (kb + 127) <= (qb + w * 16);  // wave-uniform
#pragma unroll
        for (int kg = 0; kg < 8; ++kg)
#pragma unroll
            for (int i = 0; i < 4; ++i) {
                float v = s[kg][i] * 0.125f;
                if (!interior && (kb + kg * 16 + r16) > (row0 + i)) v = -1e30f;
                s[kg][i] = v;
            }

        float mt[4];
#pragma unroll
        for (int i = 0; i < 4; ++i) mt[i] = s[0][i];
#pragma unroll
        for (int kg = 1; kg < 8; ++kg)
#pragma unroll
            for (int i = 0; i < 4; ++i) mt[i] = fmaxf(mt[i], s[kg][i]);
#pragma unroll
        for (int off = 8; off; off >>= 1)
#pragma unroll
            for (int i = 0; i < 4; ++i)
                mt[i] = fmaxf(mt[i], __shfl_xor(mt[i], off, 64));
        float alpha[4];
#pragma unroll
        for (int i = 0; i < 4; ++i) {
            float mn = fmaxf(m_i[i], mt[i]);
            alpha[i] = __expf(m_i[i] - mn);
            m_i[i] = mn;
        }
        float rs[4] = {0.f, 0.f, 0.f, 0.f};
#pragma unroll
        for (int kg = 0; kg < 8; ++kg)
#pragma unroll
            for (int i = 0; i < 4; ++i) {
                float p = __expf(s[kg][i] - m_i[i]);  // masked -> exp(-huge)=0
                s[kg][i] = p;
                rs[i] += p;
            }
#pragma unroll
        for (int off = 8; off; off >>= 1)
#pragma unroll
            for (int i = 0; i < 4; ++i) rs[i] += __shfl_xor(rs[i], off, 64);
#pragma unroll
        for (int i = 0; i < 4; ++i) l_i[i] = l_i[i] * alpha[i] + rs[i];
#pragma unroll
        for (int ci = 0; ci < 4; ++ci)
#pragma unroll
            for (int i = 0; i < 4; ++i) o[ci][i] *= alpha[i];

        // P: C-layout (row=q4*4+i, key=kg*16+r16) -> A-layout via wave-private LDS
#pragma unroll
        for (int kg = 0; kg < 8; ++kg)
#pragma unroll
            for (int i = 0; i < 4; ++i)
                lP[w][(kg * 2 + (r16 >> 3)) * 128 + (q4 * 4 + i) * 8 + (r16 & 7)] =
                    (__bf16)s[kg][i];
        __syncthreads();
#pragma unroll
        for (int q = 0; q < 4; ++q) {
            bf16x8 pf = *(const bf16x8*)&lP[w][(q * 4 + q4) * 128 + r16 * 8];
#pragma unroll
            for (int ci = 0; ci < 4; ++ci) {
                bf16x8 vf = *(const bf16x8*)&lV[(q * 4 + q4) * 512 + (ci * 16 + r16) * 8];
                o[ci] = __builtin_amdgcn_mfma_f32_16x16x32_bf16(pf, vf, o[ci], 0, 0, 0);
            }
        }
    }

#pragma unroll
    for (int ci = 0; ci < 4; ++ci)
#pragma unroll
        for (int i = 0; i < 4; ++i) {
            int trow = qb + w * 16 + q4 * 4 + i;
            float inv_l = (l_i[i] > 0.f) ? (1.f / l_i[i]) : 0.f;
            attnb[(size_t)(b * 2048 + trow) * 1024 + h * 64 + ci * 16 + r16] =
                (__bf16)(o[ci][i] * inv_l);
        }
}

// ---------------- launcher ----------------
extern "C" void kernel_launch(void* const* d_in, const int* in_sizes, int n_in,
                              void* d_out, int out_size, void* d_ws, size_t ws_size,
                              hipStream_t stream)
{
    const float* x      = (const float*)d_in[0];
    const float* ln1_g  = (const float*)d_in[1];
    const float* ln1_b  = (const float*)d_in[2];
    const float* w_qkv  = (const float*)d_in[3];
    const float* b_qkv  = (const float*)d_in[4];
    const float* w_proj = (const float*)d_in[5];
    const float* b_proj = (const float*)d_in[6];
    const float* ln2_g  = (const float*)d_in[7];
    const float* ln2_b  = (const float*)d_in[8];
    const float* w_fc   = (const float*)d_in[9];
    const float* b_fc   = (const float*)d_in[10];
    const float* w_mlp  = (const float*)d_in[11];
    const float* b_mlp  = (const float*)d_in[12];
    float* out = (float*)d_out;

    const size_t MiB = (size_t)1 << 20;
    if (ws_size < 136 * MiB) {
        float v = 1000.f + (float)(ws_size >> 20);  // report ws_size via absmax
        diag_kernel<<<(out_size + 255) / 256, 256, 0, stream>>>(out, out_size, v);
        return;
    }

    char* ws = (char*)d_ws;
    __bf16* bufA   = (__bf16*)(ws);              // 16 MiB: h -> attnb -> h2
    __bf16* bufB   = (__bf16*)(ws + 16 * MiB);   // 64 MiB: qkvb(48) -> ffb(64)
    float*  x1     = (float*) (ws + 80 * MiB);   // 32 MiB fp32 residual
    __bf16* wqkvT  = (__bf16*)(ws + 112 * MiB);  // 6 MiB  [3072,1024]
    __bf16* wprojT = (__bf16*)(ws + 118 * MiB);  // 2 MiB  [1024,1024]
    __bf16* wfcT   = (__bf16*)(ws + 120 * MiB);  // 8 MiB  [4096,1024]
    __bf16* wmlpT  = (__bf16*)(ws + 128 * MiB);  // 8 MiB  [1024,4096]

    cvtT_kernel<<<dim3(96, 32),  256, 0, stream>>>(w_qkv,  wqkvT,  1024, 3072);
    cvtT_kernel<<<dim3(32, 32),  256, 0, stream>>>(w_proj, wprojT, 1024, 1024);
    cvtT_kernel<<<dim3(128, 32), 256, 0, stream>>>(w_fc,   wfcT,   1024, 4096);
    cvtT_kernel<<<dim3(32, 128), 256, 0, stream>>>(w_mlp,  wmlpT,  4096, 1024);

    ln_kernel<<<8192, 256, 0, stream>>>(x, ln1_g, ln1_b, bufA);
    gemm_bt_kernel<0, false><<<dim3(24, 64), 256, 0, stream>>>(
        bufA, wqkvT, b_qkv, nullptr, bufB, 8192, 3072, 1024);
    attn_kernel<<<dim3(32, 64), 256, 0, stream>>>(bufB, bufA);
    gemm_bt_kernel<1, true><<<dim3(8, 64), 256, 0, stream>>>(
        bufA, wprojT, b_proj, x, x1, 8192, 1024, 1024);
    ln_kernel<<<8192, 256, 0, stream>>>(x1, ln2_g, ln2_b, bufA);
    gemm_bt_kernel<2, false><<<dim3(32, 64), 256, 0, stream>>>(
        bufA, wfcT, b_fc, nullptr, bufB, 8192, 4096, 1024);
    gemm_bt_kernel<1, true><<<dim3(8, 64), 256, 0, stream>>>(
        bufB, wmlpT, b_mlp, x1, out, 8192, 1024, 4096);
}

// Round 6
// 719.459 us; speedup vs baseline: 1.4590x; 1.1213x over previous
//
#include <hip/hip_runtime.h>
#include <hip/hip_bf16.h>

typedef __bf16 bf16x8 __attribute__((ext_vector_type(8)));
typedef __bf16 bf16x4 __attribute__((ext_vector_type(4)));
typedef float f32x4 __attribute__((ext_vector_type(4)));

#define BM 128
#define BN 128
#define BK 32

__device__ __forceinline__ void gload16(const __bf16* g, __bf16* l) {
    __builtin_amdgcn_global_load_lds((const __attribute__((address_space(1))) void*)g,
                                     (__attribute__((address_space(3))) void*)l, 16, 0, 0);
}

__device__ __forceinline__ float gelu_f(float v) {
    float z = 0.7978845608028654f * (v + 0.044715f * v * v * v);
    float e = __expf(2.f * z);
    return 0.5f * v * (2.f - 2.f / (e + 1.f));  // 0.5*v*(1+tanh(z)), overflow-safe
}

// ---------------- diagnostic fill (fp32 out) ----------------
__global__ __launch_bounds__(256) void diag_kernel(float* out, int n, float v) {
    int i = blockIdx.x * 256 + threadIdx.x;
    if (i < n) out[i] = v;
}

// ---------------- fused fp32->bf16 convert + transpose: in[K,N] -> out[N,K] ----------------
__global__ __launch_bounds__(256) void cvtT_kernel(
    const float* __restrict__ in, __bf16* __restrict__ out, int K, int N)
{
    __shared__ __bf16 tile[32][33];
    int bx = blockIdx.x * 32, by = blockIdx.y * 32;  // bx: n, by: k
    int tx = threadIdx.x & 31, ty = threadIdx.x >> 5;  // 32 x 8
#pragma unroll
    for (int i = 0; i < 32; i += 8)
        tile[ty + i][tx] = (__bf16)in[(size_t)(by + ty + i) * N + bx + tx];
    __syncthreads();
#pragma unroll
    for (int i = 0; i < 32; i += 8)
        out[(size_t)(bx + ty + i) * K + by + tx] = tile[tx][ty + i];
}

// ---------------- LayerNorm: fp32 in, bf16 out; one block per row of 1024 ----------------
__global__ __launch_bounds__(256) void ln_kernel(
    const float* __restrict__ x, const float* __restrict__ g,
    const float* __restrict__ bta, __bf16* __restrict__ out)
{
    const int row = blockIdx.x, t = threadIdx.x;
    const float* xr = x + (size_t)row * 1024;
    float4 xv = ((const float4*)xr)[t];
    float f[4] = {xv.x, xv.y, xv.z, xv.w};
    float s = f[0] + f[1] + f[2] + f[3];
    float ss = f[0]*f[0] + f[1]*f[1] + f[2]*f[2] + f[3]*f[3];
#pragma unroll
    for (int off = 32; off; off >>= 1) {
        s  += __shfl_xor(s, off, 64);
        ss += __shfl_xor(ss, off, 64);
    }
    __shared__ float red[8];
    int lane = t & 63, w = t >> 6;
    if (lane == 0) { red[w] = s; red[4 + w] = ss; }
    __syncthreads();
    s  = red[0] + red[1] + red[2] + red[3];
    ss = red[4] + red[5] + red[6] + red[7];
    float mu = s * (1.f / 1024.f);
    float var = ss * (1.f / 1024.f) - mu * mu;
    float rstd = rsqrtf(fmaxf(var, 0.f) + 1e-5f);
    float4 gv = ((const float4*)g)[t];
    float4 bv = ((const float4*)bta)[t];
    bf16x4 ov;
    ov[0] = (__bf16)((f[0] - mu) * rstd * gv.x + bv.x);
    ov[1] = (__bf16)((f[1] - mu) * rstd * gv.y + bv.y);
    ov[2] = (__bf16)((f[2] - mu) * rstd * gv.z + bv.z);
    ov[3] = (__bf16)((f[3] - mu) * rstd * gv.w + bv.w);
    ((bf16x4*)(out + (size_t)row * 1024))[t] = ov;
}

// ---------------- GEMM (m97): C[M,N] = A[M,K](bf16) @ BT[N,K]^T(bf16) + bias(f32) ----------------
template <int EPI, bool OUT32>   // EPI: 0 bias, 1 bias+res(f32), 2 bias+gelu
__global__ __launch_bounds__(256, 2) void gemm_bt_kernel(
    const __bf16* __restrict__ A, const __bf16* __restrict__ BT,
    const float* __restrict__ bias, const float* __restrict__ res,
    void* __restrict__ Cp, int M, int N, int K)
{
    __shared__ __align__(16) __bf16 lA[BM * BK];  // phys = kc*1024 + row*8 + j
    __shared__ __align__(16) __bf16 lB[BN * BK];
    const int t = threadIdx.x;
    const int lane = t & 63;
    const int wave = t >> 6;
    const int wm = wave >> 1, wn = wave & 1;
    const int q4 = lane >> 4, r16 = lane & 15;
    const int bm = blockIdx.y * BM, bn = blockIdx.x * BN;

    const int srow = t & 127;
    const int skc = t >> 7;
    const __bf16* ga0 = A + (size_t)(bm + srow) * K + skc * 8;
    const __bf16* ga1 = A + (size_t)(bm + srow) * K + (skc + 2) * 8;
    const __bf16* gb0 = BT + (size_t)(bn + srow) * K + skc * 8;
    const __bf16* gb1 = BT + (size_t)(bn + srow) * K + (skc + 2) * 8;

    f32x4 acc[4][4];
    f32x4 zero4 = {0.f, 0.f, 0.f, 0.f};
#pragma unroll
    for (int mi = 0; mi < 4; ++mi)
#pragma unroll
        for (int ni = 0; ni < 4; ++ni) acc[mi][ni] = zero4;

    for (int k0 = 0; k0 < K; k0 += BK) {
        __syncthreads();
        gload16(ga0, &lA[t * 8]);
        gload16(ga1, &lA[t * 8 + 2048]);
        gload16(gb0, &lB[t * 8]);
        gload16(gb1, &lB[t * 8 + 2048]);
        ga0 += BK; ga1 += BK; gb0 += BK; gb1 += BK;
        __syncthreads();
        bf16x8 af[4], bfr[4];
#pragma unroll
        for (int i = 0; i < 4; ++i)
            af[i] = *(const bf16x8*)&lA[q4 * 1024 + (wm * 64 + i * 16 + r16) * 8];
#pragma unroll
        for (int i = 0; i < 4; ++i)
            bfr[i] = *(const bf16x8*)&lB[q4 * 1024 + (wn * 64 + i * 16 + r16) * 8];
#pragma unroll
        for (int mi = 0; mi < 4; ++mi)
#pragma unroll
            for (int ni = 0; ni < 4; ++ni)
                acc[mi][ni] = __builtin_amdgcn_mfma_f32_16x16x32_bf16(
                    af[mi], bfr[ni], acc[mi][ni], 0, 0, 0);
    }

#pragma unroll
    for (int mi = 0; mi < 4; ++mi) {
#pragma unroll
        for (int ni = 0; ni < 4; ++ni) {
#pragma unroll
            for (int i = 0; i < 4; ++i) {
                int r = bm + wm * 64 + mi * 16 + q4 * 4 + i;
                int c = bn + wn * 64 + ni * 16 + r16;
                float v = acc[mi][ni][i] + bias[c];
                if (EPI == 1) v += res[(size_t)r * N + c];
                if (EPI == 2) v = gelu_f(v);
                if (OUT32) ((float*)Cp)[(size_t)r * N + c] = v;
                else       ((__bf16*)Cp)[(size_t)r * N + c] = (__bf16)v;
            }
        }
    }
}

// ---------------- Flash attention (causal), HD=64, T=2048, NH=16 ----------------
// qtile=128 (2 passes of 64 rows), KT=128, max-free softmax, lP chunk-recycled.
// grid: (16, B*NH); block 256 (4 waves)
__global__ __launch_bounds__(256, 4) void attn_kernel(
    const __bf16* __restrict__ qkv, __bf16* __restrict__ attnb)
{
    __shared__ __align__(16) __bf16 lK[8192];    // phys = (d>>3)*1024 + key*8 + (d&7)
    __shared__ __align__(16) __bf16 lV[8192];    // phys = (key>>3)*512 + d*8 + (key&7)
    __shared__ __align__(16) __bf16 lP[4][512];  // per-wave chunk: ((k32>>3)*128 + row*8 + (k32&7))

    const int t = threadIdx.x, lane = t & 63, w = t >> 6;
    const int q4 = lane >> 4, r16 = lane & 15;
    const int b = blockIdx.y >> 4, h = blockIdx.y & 15;
    const int qt = (blockIdx.x + (blockIdx.y >> 4) * 4) & 15;  // per-CU qt mix
    const int qb = qt * 128;
    const __bf16* Qb = qkv + (size_t)b * 2048 * 3072 + h * 64;
    const __bf16* Kb = Qb + 1024;
    const __bf16* Vb = Qb + 2048;

    // Q fragments for both passes, pre-scaled by 1/sqrt(64)=0.125 (exact in bf16)
    bf16x8 qf[2][2];
#pragma unroll
    for (int p = 0; p < 2; ++p) {
        int qrow = qb + p * 64 + w * 16 + r16;
        qf[p][0] = *(const bf16x8*)(Qb + (size_t)qrow * 3072 + q4 * 8);
        qf[p][1] = *(const bf16x8*)(Qb + (size_t)qrow * 3072 + 32 + q4 * 8);
#pragma unroll
        for (int j = 0; j < 8; ++j) {
            qf[p][0][j] = (__bf16)((float)qf[p][0][j] * 0.125f);
            qf[p][1][j] = (__bf16)((float)qf[p][1][j] * 0.125f);
        }
    }

    f32x4 zero4 = {0.f, 0.f, 0.f, 0.f};
    f32x4 o[2][4];
    float rs[2][4];
#pragma unroll
    for (int p = 0; p < 2; ++p)
#pragma unroll
        for (int i = 0; i < 4; ++i) { o[p][i] = zero4; rs[p][i] = 0.f; }

    const int skey = t & 127;
    const int vkc = t >> 6, svd = t & 63;

    for (int kb = 0; kb < qb + 128; kb += 128) {
        __syncthreads();
#pragma unroll
        for (int c = 0; c < 4; ++c)
            gload16(Kb + (size_t)(kb + skey) * 3072 + (c * 2 + (t >> 7)) * 8,
                    &lK[c * 2048 + t * 8]);
#pragma unroll
        for (int c = 0; c < 4; ++c) {
            int kc = c * 4 + vkc;
            bf16x8 vt;
#pragma unroll
            for (int j = 0; j < 8; ++j)
                vt[j] = Vb[(size_t)(kb + kc * 8 + j) * 3072 + svd];
            *(bf16x8*)&lV[kc * 512 + svd * 8] = vt;
        }
        __syncthreads();

#pragma unroll
        for (int p = 0; p < 2; ++p) {
            const int row0 = qb + p * 64 + w * 16 + q4 * 4;
            const bool interior = (kb + 127) <= (qb + p * 64 + w * 16);  // wave-uniform

            // QK^T: S[16 q x 128 key]
            f32x4 s[8];
#pragma unroll
            for (int kg = 0; kg < 8; ++kg) {
                bf16x8 kfA = *(const bf16x8*)&lK[q4 * 1024 + (kg * 16 + r16) * 8];
                bf16x8 kfB = *(const bf16x8*)&lK[(4 + q4) * 1024 + (kg * 16 + r16) * 8];
                s[kg] = __builtin_amdgcn_mfma_f32_16x16x32_bf16(qf[p][0], kfA, zero4, 0, 0, 0);
                s[kg] = __builtin_amdgcn_mfma_f32_16x16x32_bf16(qf[p][1], kfB, s[kg], 0, 0, 0);
            }

            // max-free softmax: p = exp(min(s,75)), masked -> 0; accumulate per-lane l partials
#pragma unroll
            for (int kg = 0; kg < 8; ++kg)
#pragma unroll
                for (int i = 0; i < 4; ++i) {
                    float e = __expf(fminf(s[kg][i], 75.f));
                    if (!interior && (kb + kg * 16 + r16) > (row0 + i)) e = 0.f;
                    s[kg][i] = e;
                    rs[p][i] += e;
                }

            // PV per 32-key chunk: P C-layout -> A-layout via wave-private lP (1KB)
#pragma unroll
            for (int c = 0; c < 4; ++c) {
#pragma unroll
                for (int kh = 0; kh < 2; ++kh)
#pragma unroll
                    for (int i = 0; i < 4; ++i)
                        lP[w][(kh * 2 + (r16 >> 3)) * 128 + (q4 * 4 + i) * 8 + (r16 & 7)] =
                            (__bf16)s[c * 2 + kh][i];
                asm volatile("s_waitcnt lgkmcnt(0)" ::: "memory");
                bf16x8 pf = *(const bf16x8*)&lP[w][q4 * 128 + r16 * 8];
#pragma unroll
                for (int ci = 0; ci < 4; ++ci) {
                    bf16x8 vf = *(const bf16x8*)&lV[(c * 4 + q4) * 512 + (ci * 16 + r16) * 8];
                    o[p][ci] = __builtin_amdgcn_mfma_f32_16x16x32_bf16(pf, vf, o[p][ci], 0, 0, 0);
                }
            }
        }
    }

#pragma unroll
    for (int p = 0; p < 2; ++p) {
#pragma unroll
        for (int off = 8; off; off >>= 1)
#pragma unroll
            for (int i = 0; i < 4; ++i) rs[p][i] += __shfl_xor(rs[p][i], off, 64);
#pragma unroll
        for (int ci = 0; ci < 4; ++ci)
#pragma unroll
            for (int i = 0; i < 4; ++i) {
                int trow = qb + p * 64 + w * 16 + q4 * 4 + i;
                float inv_l = (rs[p][i] > 0.f) ? (1.f / rs[p][i]) : 0.f;
                attnb[(size_t)(b * 2048 + trow) * 1024 + h * 64 + ci * 16 + r16] =
                    (__bf16)(o[p][ci][i] * inv_l);
            }
    }
}

// ---------------- launcher ----------------
extern "C" void kernel_launch(void* const* d_in, const int* in_sizes, int n_in,
                              void* d_out, int out_size, void* d_ws, size_t ws_size,
                              hipStream_t stream)
{
    const float* x      = (const float*)d_in[0];
    const float* ln1_g  = (const float*)d_in[1];
    const float* ln1_b  = (const float*)d_in[2];
    const float* w_qkv  = (const float*)d_in[3];
    const float* b_qkv  = (const float*)d_in[4];
    const float* w_proj = (const float*)d_in[5];
    const float* b_proj = (const float*)d_in[6];
    const float* ln2_g  = (const float*)d_in[7];
    const float* ln2_b  = (const float*)d_in[8];
    const float* w_fc   = (const float*)d_in[9];
    const float* b_fc   = (const float*)d_in[10];
    const float* w_mlp  = (const float*)d_in[11];
    const float* b_mlp  = (const float*)d_in[12];
    float* out = (float*)d_out;

    const size_t MiB = (size_t)1 << 20;
    if (ws_size < 136 * MiB) {
        float v = 1000.f + (float)(ws_size >> 20);
        diag_kernel<<<(out_size + 255) / 256, 256, 0, stream>>>(out, out_size, v);
        return;
    }

    char* ws = (char*)d_ws;
    __bf16* bufA   = (__bf16*)(ws);              // 16 MiB: h -> attnb -> h2
    __bf16* bufB   = (__bf16*)(ws + 16 * MiB);   // 64 MiB: qkvb(48) -> ffb(64)
    float*  x1     = (float*) (ws + 80 * MiB);   // 32 MiB fp32 residual
    __bf16* wqkvT  = (__bf16*)(ws + 112 * MiB);  // 6 MiB
    __bf16* wprojT = (__bf16*)(ws + 118 * MiB);  // 2 MiB
    __bf16* wfcT   = (__bf16*)(ws + 120 * MiB);  // 8 MiB
    __bf16* wmlpT  = (__bf16*)(ws + 128 * MiB);  // 8 MiB

    cvtT_kernel<<<dim3(96, 32),  256, 0, stream>>>(w_qkv,  wqkvT,  1024, 3072);
    cvtT_kernel<<<dim3(32, 32),  256, 0, stream>>>(w_proj, wprojT, 1024, 1024);
    cvtT_kernel<<<dim3(128, 32), 256, 0, stream>>>(w_fc,   wfcT,   1024, 4096);
    cvtT_kernel<<<dim3(32, 128), 256, 0, stream>>>(w_mlp,  wmlpT,  4096, 1024);

    ln_kernel<<<8192, 256, 0, stream>>>(x, ln1_g, ln1_b, bufA);
    gemm_bt_kernel<0, false><<<dim3(24, 64), 256, 0, stream>>>(
        bufA, wqkvT, b_qkv, nullptr, bufB, 8192, 3072, 1024);
    attn_kernel<<<dim3(16, 64), 256, 0, stream>>>(bufB, bufA);
    gemm_bt_kernel<1, true><<<dim3(8, 64), 256, 0, stream>>>(
        bufA, wprojT, b_proj, x, x1, 8192, 1024, 1024);
    ln_kernel<<<8192, 256, 0, stream>>>(x1, ln2_g, ln2_b, bufA);
    gemm_bt_kernel<2, false><<<dim3(32, 64), 256, 0, stream>>>(
        bufA, wfcT, b_fc, nullptr, bufB, 8192, 4096, 1024);
    gemm_bt_kernel<1, true><<<dim3(8, 64), 256, 0, stream>>>(
        bufB, wmlpT, b_mlp, x1, out, 8192, 1024, 4096);
}

// Round 7
// 716.119 us; speedup vs baseline: 1.4658x; 1.0047x over previous
//
#include <hip/hip_runtime.h>
#include <hip/hip_bf16.h>

typedef __bf16 bf16x8 __attribute__((ext_vector_type(8)));
typedef __bf16 bf16x4 __attribute__((ext_vector_type(4)));
typedef float f32x4 __attribute__((ext_vector_type(4)));

#define BM 128
#define BN 128
#define BK 32

__device__ __forceinline__ void gload16(const __bf16* g, __bf16* l) {
    __builtin_amdgcn_global_load_lds((const __attribute__((address_space(1))) void*)g,
                                     (__attribute__((address_space(3))) void*)l, 16, 0, 0);
}

__device__ __forceinline__ float gelu_f(float v) {
    float z = 0.7978845608028654f * (v + 0.044715f * v * v * v);
    float e = __expf(2.f * z);
    return 0.5f * v * (2.f - 2.f / (e + 1.f));  // 0.5*v*(1+tanh(z)), overflow-safe
}

// ---------------- diagnostic fill (fp32 out) ----------------
__global__ __launch_bounds__(256) void diag_kernel(float* out, int n, float v) {
    int i = blockIdx.x * 256 + threadIdx.x;
    if (i < n) out[i] = v;
}

// ---------------- fused fp32->bf16 convert + transpose: in[K,N] -> out[N,K] ----------------
__global__ __launch_bounds__(256) void cvtT_kernel(
    const float* __restrict__ in, __bf16* __restrict__ out, int K, int N)
{
    __shared__ __bf16 tile[32][33];
    int bx = blockIdx.x * 32, by = blockIdx.y * 32;  // bx: n, by: k
    int tx = threadIdx.x & 31, ty = threadIdx.x >> 5;  // 32 x 8
#pragma unroll
    for (int i = 0; i < 32; i += 8)
        tile[ty + i][tx] = (__bf16)in[(size_t)(by + ty + i) * N + bx + tx];
    __syncthreads();
#pragma unroll
    for (int i = 0; i < 32; i += 8)
        out[(size_t)(bx + ty + i) * K + by + tx] = tile[tx][ty + i];
}

// ---------------- LayerNorm: fp32 in, bf16 out; one block per row of 1024 ----------------
__global__ __launch_bounds__(256) void ln_kernel(
    const float* __restrict__ x, const float* __restrict__ g,
    const float* __restrict__ bta, __bf16* __restrict__ out)
{
    const int row = blockIdx.x, t = threadIdx.x;
    const float* xr = x + (size_t)row * 1024;
    float4 xv = ((const float4*)xr)[t];
    float f[4] = {xv.x, xv.y, xv.z, xv.w};
    float s = f[0] + f[1] + f[2] + f[3];
    float ss = f[0]*f[0] + f[1]*f[1] + f[2]*f[2] + f[3]*f[3];
#pragma unroll
    for (int off = 32; off; off >>= 1) {
        s  += __shfl_xor(s, off, 64);
        ss += __shfl_xor(ss, off, 64);
    }
    __shared__ float red[8];
    int lane = t & 63, w = t >> 6;
    if (lane == 0) { red[w] = s; red[4 + w] = ss; }
    __syncthreads();
    s  = red[0] + red[1] + red[2] + red[3];
    ss = red[4] + red[5] + red[6] + red[7];
    float mu = s * (1.f / 1024.f);
    float var = ss * (1.f / 1024.f) - mu * mu;
    float rstd = rsqrtf(fmaxf(var, 0.f) + 1e-5f);
    float4 gv = ((const float4*)g)[t];
    float4 bv = ((const float4*)bta)[t];
    bf16x4 ov;
    ov[0] = (__bf16)((f[0] - mu) * rstd * gv.x + bv.x);
    ov[1] = (__bf16)((f[1] - mu) * rstd * gv.y + bv.y);
    ov[2] = (__bf16)((f[2] - mu) * rstd * gv.z + bv.z);
    ov[3] = (__bf16)((f[3] - mu) * rstd * gv.w + bv.w);
    ((bf16x4*)(out + (size_t)row * 1024))[t] = ov;
}

// ---------------- GEMM 128x128 (m97): C = A @ BT^T + bias ----------------
template <int EPI, bool OUT32>   // EPI: 0 bias, 1 bias+res(f32), 2 bias+gelu
__global__ __launch_bounds__(256, 4) void gemm_bt_kernel(
    const __bf16* __restrict__ A, const __bf16* __restrict__ BT,
    const float* __restrict__ bias, const float* __restrict__ res,
    void* __restrict__ Cp, int M, int N, int K)
{
    __shared__ __align__(16) __bf16 lA[BM * BK];  // phys = kc*1024 + row*8 + j
    __shared__ __align__(16) __bf16 lB[BN * BK];
    const int t = threadIdx.x;
    const int lane = t & 63;
    const int wave = t >> 6;
    const int wm = wave >> 1, wn = wave & 1;
    const int q4 = lane >> 4, r16 = lane & 15;
    const int bm = blockIdx.y * BM, bn = blockIdx.x * BN;

    const int srow = t & 127;
    const int skc = t >> 7;
    const __bf16* ga0 = A + (size_t)(bm + srow) * K + skc * 8;
    const __bf16* ga1 = A + (size_t)(bm + srow) * K + (skc + 2) * 8;
    const __bf16* gb0 = BT + (size_t)(bn + srow) * K + skc * 8;
    const __bf16* gb1 = BT + (size_t)(bn + srow) * K + (skc + 2) * 8;

    f32x4 acc[4][4];
    f32x4 zero4 = {0.f, 0.f, 0.f, 0.f};
#pragma unroll
    for (int mi = 0; mi < 4; ++mi)
#pragma unroll
        for (int ni = 0; ni < 4; ++ni) acc[mi][ni] = zero4;

    for (int k0 = 0; k0 < K; k0 += BK) {
        __syncthreads();
        gload16(ga0, &lA[t * 8]);
        gload16(ga1, &lA[t * 8 + 2048]);
        gload16(gb0, &lB[t * 8]);
        gload16(gb1, &lB[t * 8 + 2048]);
        ga0 += BK; ga1 += BK; gb0 += BK; gb1 += BK;
        __syncthreads();
        bf16x8 af[4], bfr[4];
#pragma unroll
        for (int i = 0; i < 4; ++i)
            af[i] = *(const bf16x8*)&lA[q4 * 1024 + (wm * 64 + i * 16 + r16) * 8];
#pragma unroll
        for (int i = 0; i < 4; ++i)
            bfr[i] = *(const bf16x8*)&lB[q4 * 1024 + (wn * 64 + i * 16 + r16) * 8];
#pragma unroll
        for (int mi = 0; mi < 4; ++mi)
#pragma unroll
            for (int ni = 0; ni < 4; ++ni)
                acc[mi][ni] = __builtin_amdgcn_mfma_f32_16x16x32_bf16(
                    af[mi], bfr[ni], acc[mi][ni], 0, 0, 0);
    }

#pragma unroll
    for (int mi = 0; mi < 4; ++mi) {
#pragma unroll
        for (int ni = 0; ni < 4; ++ni) {
#pragma unroll
            for (int i = 0; i < 4; ++i) {
                int r = bm + wm * 64 + mi * 16 + q4 * 4 + i;
                int c = bn + wn * 64 + ni * 16 + r16;
                float v = acc[mi][ni][i] + bias[c];
                if (EPI == 1) v += res[(size_t)r * N + c];
                if (EPI == 2) v = gelu_f(v);
                if (OUT32) ((float*)Cp)[(size_t)r * N + c] = v;
                else       ((__bf16*)Cp)[(size_t)r * N + c] = (__bf16)v;
            }
        }
    }
}

// ---------------- GEMM 128x256 wide: for N-fat layers (qkv, fc) ----------------
// 4 waves in 2x2; each wave 64Mx128N = 4x8 acc. 128 MFMA per K-iter vs 6 staging loads.
template <int EPI, bool OUT32>
__global__ __launch_bounds__(256, 2) void gemm_bt_wide_kernel(
    const __bf16* __restrict__ A, const __bf16* __restrict__ BT,
    const float* __restrict__ bias, const float* __restrict__ res,
    void* __restrict__ Cp, int M, int N, int K)
{
    __shared__ __align__(16) __bf16 lA[128 * BK];  // phys = kc*1024 + row*8 + j
    __shared__ __align__(16) __bf16 lB[256 * BK];  // phys = kc*2048 + row*8 + j
    const int t = threadIdx.x;
    const int lane = t & 63;
    const int wave = t >> 6;
    const int wm = wave >> 1, wn = wave & 1;      // wave tile: rows wm*64, cols wn*128
    const int q4 = lane >> 4, r16 = lane & 15;
    const int bm = blockIdx.y * 128, bn = blockIdx.x * 256;

    const int srow = t & 127;
    const int skc = t >> 7;
    const __bf16* ga0 = A + (size_t)(bm + srow) * K + skc * 8;
    const __bf16* ga1 = A + (size_t)(bm + srow) * K + (skc + 2) * 8;
    const __bf16* gb  = BT + (size_t)(bn + t) * K;

    f32x4 acc[4][8];
    f32x4 zero4 = {0.f, 0.f, 0.f, 0.f};
#pragma unroll
    for (int mi = 0; mi < 4; ++mi)
#pragma unroll
        for (int ni = 0; ni < 8; ++ni) acc[mi][ni] = zero4;

    for (int k0 = 0; k0 < K; k0 += BK) {
        __syncthreads();
        gload16(ga0, &lA[t * 8]);
        gload16(ga1, &lA[t * 8 + 2048]);
#pragma unroll
        for (int c = 0; c < 4; ++c)
            gload16(gb + c * 8, &lB[c * 2048 + t * 8]);
        ga0 += BK; ga1 += BK; gb += BK;
        __syncthreads();
        bf16x8 af[4], bfr[8];
#pragma unroll
        for (int i = 0; i < 4; ++i)
            af[i] = *(const bf16x8*)&lA[q4 * 1024 + (wm * 64 + i * 16 + r16) * 8];
#pragma unroll
        for (int i = 0; i < 8; ++i)
            bfr[i] = *(const bf16x8*)&lB[q4 * 2048 + (wn * 128 + i * 16 + r16) * 8];
#pragma unroll
        for (int mi = 0; mi < 4; ++mi)
#pragma unroll
            for (int ni = 0; ni < 8; ++ni)
                acc[mi][ni] = __builtin_amdgcn_mfma_f32_16x16x32_bf16(
                    af[mi], bfr[ni], acc[mi][ni], 0, 0, 0);
    }

#pragma unroll
    for (int mi = 0; mi < 4; ++mi) {
#pragma unroll
        for (int ni = 0; ni < 8; ++ni) {
#pragma unroll
            for (int i = 0; i < 4; ++i) {
                int r = bm + wm * 64 + mi * 16 + q4 * 4 + i;
                int c = bn + wn * 128 + ni * 16 + r16;
                float v = acc[mi][ni][i] + bias[c];
                if (EPI == 1) v += res[(size_t)r * N + c];
                if (EPI == 2) v = gelu_f(v);
                if (OUT32) ((float*)Cp)[(size_t)r * N + c] = v;
                else       ((__bf16*)Cp)[(size_t)r * N + c] = (__bf16)v;
            }
        }
    }
}

// ---------------- Flash attention (causal), HD=64, T=2048, NH=16 ----------------
// qtile=128 (2 passes of 64 rows), KT=128, max-free softmax, lP chunk-recycled.
__global__ __launch_bounds__(256, 4) void attn_kernel(
    const __bf16* __restrict__ qkv, __bf16* __restrict__ attnb)
{
    __shared__ __align__(16) __bf16 lK[8192];    // phys = (d>>3)*1024 + key*8 + (d&7)
    __shared__ __align__(16) __bf16 lV[8192];    // phys = (key>>3)*512 + d*8 + (key&7)
    __shared__ __align__(16) __bf16 lP[4][512];  // per-wave 32-key chunk

    const int t = threadIdx.x, lane = t & 63, w = t >> 6;
    const int q4 = lane >> 4, r16 = lane & 15;
    const int b = blockIdx.y >> 4, h = blockIdx.y & 15;
    const int qt = (blockIdx.x + (blockIdx.y >> 4) * 4) & 15;  // per-CU qt mix
    const int qb = qt * 128;
    const __bf16* Qb = qkv + (size_t)b * 2048 * 3072 + h * 64;
    const __bf16* Kb = Qb + 1024;
    const __bf16* Vb = Qb + 2048;

    bf16x8 qf[2][2];
#pragma unroll
    for (int p = 0; p < 2; ++p) {
        int qrow = qb + p * 64 + w * 16 + r16;
        qf[p][0] = *(const bf16x8*)(Qb + (size_t)qrow * 3072 + q4 * 8);
        qf[p][1] = *(const bf16x8*)(Qb + (size_t)qrow * 3072 + 32 + q4 * 8);
#pragma unroll
        for (int j = 0; j < 8; ++j) {
            qf[p][0][j] = (__bf16)((float)qf[p][0][j] * 0.125f);
            qf[p][1][j] = (__bf16)((float)qf[p][1][j] * 0.125f);
        }
    }

    f32x4 zero4 = {0.f, 0.f, 0.f, 0.f};
    f32x4 o[2][4];
    float rs[2][4];
#pragma unroll
    for (int p = 0; p < 2; ++p)
#pragma unroll
        for (int i = 0; i < 4; ++i) { o[p][i] = zero4; rs[p][i] = 0.f; }

    const int skey = t & 127;
    const int vkc = t >> 6, svd = t & 63;

    for (int kb = 0; kb < qb + 128; kb += 128) {
        __syncthreads();
#pragma unroll
        for (int c = 0; c < 4; ++c)
            gload16(Kb + (size_t)(kb + skey) * 3072 + (c * 2 + (t >> 7)) * 8,
                    &lK[c * 2048 + t * 8]);
#pragma unroll
        for (int c = 0; c < 4; ++c) {
            int kc = c * 4 + vkc;
            bf16x8 vt;
#pragma unroll
            for (int j = 0; j < 8; ++j)
                vt[j] = Vb[(size_t)(kb + kc * 8 + j) * 3072 + svd];
            *(bf16x8*)&lV[kc * 512 + svd * 8] = vt;
        }
        __syncthreads();

#pragma unroll
        for (int p = 0; p < 2; ++p) {
            const int row0 = qb + p * 64 + w * 16 + q4 * 4;
            const bool interior = (kb + 127) <= (qb + p * 64 + w * 16);  // wave-uniform

            f32x4 s[8];
#pragma unroll
            for (int kg = 0; kg < 8; ++kg) {
                bf16x8 kfA = *(const bf16x8*)&lK[q4 * 1024 + (kg * 16 + r16) * 8];
                bf16x8 kfB = *(const bf16x8*)&lK[(4 + q4) * 1024 + (kg * 16 + r16) * 8];
                s[kg] = __builtin_amdgcn_mfma_f32_16x16x32_bf16(qf[p][0], kfA, zero4, 0, 0, 0);
                s[kg] = __builtin_amdgcn_mfma_f32_16x16x32_bf16(qf[p][1], kfB, s[kg], 0, 0, 0);
            }

#pragma unroll
            for (int kg = 0; kg < 8; ++kg)
#pragma unroll
                for (int i = 0; i < 4; ++i) {
                    float e = __expf(fminf(s[kg][i], 75.f));
                    if (!interior && (kb + kg * 16 + r16) > (row0 + i)) e = 0.f;
                    s[kg][i] = e;
                    rs[p][i] += e;
                }

#pragma unroll
            for (int c = 0; c < 4; ++c) {
#pragma unroll
                for (int kh = 0; kh < 2; ++kh)
#pragma unroll
                    for (int i = 0; i < 4; ++i)
                        lP[w][(kh * 2 + (r16 >> 3)) * 128 + (q4 * 4 + i) * 8 + (r16 & 7)] =
                            (__bf16)s[c * 2 + kh][i];
                asm volatile("s_waitcnt lgkmcnt(0)" ::: "memory");
                bf16x8 pf = *(const bf16x8*)&lP[w][q4 * 128 + r16 * 8];
#pragma unroll
                for (int ci = 0; ci < 4; ++ci) {
                    bf16x8 vf = *(const bf16x8*)&lV[(c * 4 + q4) * 512 + (ci * 16 + r16) * 8];
                    o[p][ci] = __builtin_amdgcn_mfma_f32_16x16x32_bf16(pf, vf, o[p][ci], 0, 0, 0);
                }
            }
        }
    }

#pragma unroll
    for (int p = 0; p < 2; ++p) {
#pragma unroll
        for (int off = 8; off; off >>= 1)
#pragma unroll
            for (int i = 0; i < 4; ++i) rs[p][i] += __shfl_xor(rs[p][i], off, 64);
#pragma unroll
        for (int ci = 0; ci < 4; ++ci)
#pragma unroll
            for (int i = 0; i < 4; ++i) {
                int trow = qb + p * 64 + w * 16 + q4 * 4 + i;
                float inv_l = (rs[p][i] > 0.f) ? (1.f / rs[p][i]) : 0.f;
                attnb[(size_t)(b * 2048 + trow) * 1024 + h * 64 + ci * 16 + r16] =
                    (__bf16)(o[p][ci][i] * inv_l);
            }
    }
}

// ---------------- launcher ----------------
extern "C" void kernel_launch(void* const* d_in, const int* in_sizes, int n_in,
                              void* d_out, int out_size, void* d_ws, size_t ws_size,
                              hipStream_t stream)
{
    const float* x      = (const float*)d_in[0];
    const float* ln1_g  = (const float*)d_in[1];
    const float* ln1_b  = (const float*)d_in[2];
    const float* w_qkv  = (const float*)d_in[3];
    const float* b_qkv  = (const float*)d_in[4];
    const float* w_proj = (const float*)d_in[5];
    const float* b_proj = (const float*)d_in[6];
    const float* ln2_g  = (const float*)d_in[7];
    const float* ln2_b  = (const float*)d_in[8];
    const float* w_fc   = (const float*)d_in[9];
    const float* b_fc   = (const float*)d_in[10];
    const float* w_mlp  = (const float*)d_in[11];
    const float* b_mlp  = (const float*)d_in[12];
    float* out = (float*)d_out;

    const size_t MiB = (size_t)1 << 20;
    if (ws_size < 136 * MiB) {
        float v = 1000.f + (float)(ws_size >> 20);
        diag_kernel<<<(out_size + 255) / 256, 256, 0, stream>>>(out, out_size, v);
        return;
    }

    char* ws = (char*)d_ws;
    __bf16* bufA   = (__bf16*)(ws);              // 16 MiB: h -> attnb -> h2
    __bf16* bufB   = (__bf16*)(ws + 16 * MiB);   // 64 MiB: qkvb(48) -> ffb(64)
    float*  x1     = (float*) (ws + 80 * MiB);   // 32 MiB fp32 residual
    __bf16* wqkvT  = (__bf16*)(ws + 112 * MiB);  // 6 MiB
    __bf16* wprojT = (__bf16*)(ws + 118 * MiB);  // 2 MiB
    __bf16* wfcT   = (__bf16*)(ws + 120 * MiB);  // 8 MiB
    __bf16* wmlpT  = (__bf16*)(ws + 128 * MiB);  // 8 MiB

    cvtT_kernel<<<dim3(96, 32),  256, 0, stream>>>(w_qkv,  wqkvT,  1024, 3072);
    cvtT_kernel<<<dim3(32, 32),  256, 0, stream>>>(w_proj, wprojT, 1024, 1024);
    cvtT_kernel<<<dim3(128, 32), 256, 0, stream>>>(w_fc,   wfcT,   1024, 4096);
    cvtT_kernel<<<dim3(32, 128), 256, 0, stream>>>(w_mlp,  wmlpT,  4096, 1024);

    ln_kernel<<<8192, 256, 0, stream>>>(x, ln1_g, ln1_b, bufA);
    gemm_bt_wide_kernel<0, false><<<dim3(12, 64), 256, 0, stream>>>(
        bufA, wqkvT, b_qkv, nullptr, bufB, 8192, 3072, 1024);
    attn_kernel<<<dim3(16, 64), 256, 0, stream>>>(bufB, bufA);
    gemm_bt_kernel<1, true><<<dim3(8, 64), 256, 0, stream>>>(
        bufA, wprojT, b_proj, x, x1, 8192, 1024, 1024);
    ln_kernel<<<8192, 256, 0, stream>>>(x1, ln2_g, ln2_b, bufA);
    gemm_bt_wide_kernel<2, false><<<dim3(16, 64), 256, 0, stream>>>(
        bufA, wfcT, b_fc, nullptr, bufB, 8192, 4096, 1024);
    gemm_bt_kernel<1, true><<<dim3(8, 64), 256, 0, stream>>>(
        bufB, wmlpT, b_mlp, x1, out, 8192, 1024, 4096);
}